// Round 1
// baseline (1566.189 us; speedup 1.0000x reference)
//
#include <hip/hip_runtime.h>

// Problem constants (fixed by reference)
#define NND 4096            // nodes N
#define NED 4096            // hyperedges E
#define NNZK 32768          // nnz
#define BB 64               // batch
#define CC 256              // channels
#define MM (NND * BB)       // 262144 GEMM rows

typedef __attribute__((ext_vector_type(8))) __bf16 bf16x8;
typedef __attribute__((ext_vector_type(4))) float f32x4;

__device__ __forceinline__ float b2f(unsigned short h) {
  unsigned int v = ((unsigned int)h) << 16;
  return __builtin_bit_cast(float, v);
}
__device__ __forceinline__ unsigned short f2b(float f) {
  unsigned int v = __builtin_bit_cast(unsigned int, f);
  v = v + 0x7FFFu + ((v >> 16) & 1u);
  return (unsigned short)(v >> 16);
}

// ---- CSR build -------------------------------------------------------------
__global__ __launch_bounds__(256) void hist_k(const int* __restrict__ src,
                                              const int* __restrict__ dst,
                                              int* __restrict__ DdegI,
                                              int* __restrict__ BdegI) {
  int i = blockIdx.x * 256 + threadIdx.x;   // grid exactly NNZK threads
  atomicAdd(&DdegI[src[i]], 1);
  atomicAdd(&BdegI[dst[i]], 1);
}

// block 0: edge array (Bdeg), block 1: node array (Ddeg); n = 4096 each
__global__ __launch_bounds__(256) void scan_k(const int* __restrict__ degB, int* __restrict__ offB,
                                              int* __restrict__ curB, float* __restrict__ invB,
                                              const int* __restrict__ degD, int* __restrict__ offD,
                                              int* __restrict__ curD, float* __restrict__ invD) {
  const int* deg; int* off; int* cur; float* inv;
  if (blockIdx.x == 0) { deg = degB; off = offB; cur = curB; inv = invB; }
  else                 { deg = degD; off = offD; cur = curD; inv = invD; }
  int t = threadIdx.x;
  int base = t * 16;
  int v[16]; int s = 0;
  #pragma unroll
  for (int i = 0; i < 16; ++i) { v[i] = deg[base + i]; s += v[i]; }
  __shared__ int sm[256];
  sm[t] = s;
  __syncthreads();
  for (int d = 1; d < 256; d <<= 1) {
    int x = (t >= d) ? sm[t - d] : 0;
    __syncthreads();
    sm[t] += x;
    __syncthreads();
  }
  int excl = sm[t] - s;
  #pragma unroll
  for (int i = 0; i < 16; ++i) {
    off[base + i] = excl;
    cur[base + i] = excl;
    int dv = v[i];
    inv[base + i] = (dv > 0) ? (1.0f / (float)dv) : 0.0f;
    excl += dv;
  }
  if (t == 255) off[4096] = excl;
}

__global__ __launch_bounds__(256) void fill_k(const int* __restrict__ src,
                                              const int* __restrict__ dst,
                                              int* __restrict__ curB, int* __restrict__ curD,
                                              int* __restrict__ listB, int* __restrict__ listD) {
  int i = blockIdx.x * 256 + threadIdx.x;
  int s = src[i], d = dst[i];
  int p = atomicAdd(&curB[d], 1);
  listB[p] = s;                      // CSR over edges: contributing node ids
  int q = atomicAdd(&curD[s], 1);
  listD[q] = d;                      // CSR over nodes: contributing edge ids
}

// ---- dtype/layout converts -------------------------------------------------
// x [b][n][c] fp32 -> xb bf16 rows r = n*64+b (node-major)
__global__ __launch_bounds__(256) void cvt_x_k(const float* __restrict__ x,
                                               unsigned short* __restrict__ xb) {
  int blk = blockIdx.x * 4 + (threadIdx.x >> 6);  // row id in [0, B*N), b-major
  int b = blk >> 12, n = blk & 4095;
  int t = threadIdx.x & 63;
  float4 v = *(const float4*)(x + (size_t)blk * CC + t * 4);
  ushort4 o;
  o.x = f2b(v.x); o.y = f2b(v.y); o.z = f2b(v.z); o.w = f2b(v.w);
  *(ushort4*)(xb + (((size_t)n << 6) + b) * CC + t * 4) = o;
}

// W [k][n] fp32 -> Wt bf16 [n][k]
__global__ __launch_bounds__(256) void cvt_w_k(const float* __restrict__ W,
                                               unsigned short* __restrict__ Wt) {
  int k = blockIdx.x, n = threadIdx.x;
  Wt[n * CC + k] = f2b(W[k * CC + n]);
}

// ---- bf16 MFMA GEMM: C[m][n] = sum_k A[m][k] * Bt[n][k] --------------------
// A: [MM, 256] bf16, Bt: [256,256] bf16 (transposed weights), C: [MM,256] bf16
__global__ __launch_bounds__(256) void gemm_tn(const unsigned short* __restrict__ A,
                                               const unsigned short* __restrict__ Bt,
                                               unsigned short* __restrict__ C) {
  __shared__ __align__(16) unsigned short Al[64][40];  // +8 pad: 2-way banks (free)
  __shared__ __align__(16) unsigned short Bl[64][40];
  int t = threadIdx.x;
  int w = t >> 6, l = t & 63;
  int m0 = blockIdx.x * 64, n0 = blockIdx.y * 64;
  f32x4 acc0 = {0.f, 0.f, 0.f, 0.f};
  f32x4 acc1 = acc0, acc2 = acc0, acc3 = acc0;
  int srow = t >> 2, sch = (t & 3) * 8;   // staging: 64 rows x 32 k, 16B/thread
  int ml = l & 15, ko = (l >> 4) * 8;
  for (int kt = 0; kt < 8; ++kt) {
    uint4 va = *(const uint4*)(A  + (size_t)(m0 + srow) * CC + kt * 32 + sch);
    uint4 vb = *(const uint4*)(Bt + (size_t)(n0 + srow) * CC + kt * 32 + sch);
    __syncthreads();                       // prev iter's ds_reads done
    *(uint4*)&Al[srow][sch] = va;
    *(uint4*)&Bl[srow][sch] = vb;
    __syncthreads();
    bf16x8 af = __builtin_bit_cast(bf16x8, *(const uint4*)&Al[w * 16 + ml][ko]);
    bf16x8 b0 = __builtin_bit_cast(bf16x8, *(const uint4*)&Bl[ 0 + ml][ko]);
    bf16x8 b1 = __builtin_bit_cast(bf16x8, *(const uint4*)&Bl[16 + ml][ko]);
    bf16x8 b2 = __builtin_bit_cast(bf16x8, *(const uint4*)&Bl[32 + ml][ko]);
    bf16x8 b3 = __builtin_bit_cast(bf16x8, *(const uint4*)&Bl[48 + ml][ko]);
    acc0 = __builtin_amdgcn_mfma_f32_16x16x32_bf16(af, b0, acc0, 0, 0, 0);
    acc1 = __builtin_amdgcn_mfma_f32_16x16x32_bf16(af, b1, acc1, 0, 0, 0);
    acc2 = __builtin_amdgcn_mfma_f32_16x16x32_bf16(af, b2, acc2, 0, 0, 0);
    acc3 = __builtin_amdgcn_mfma_f32_16x16x32_bf16(af, b3, acc3, 0, 0, 0);
  }
  // C/D layout (verified m89): col = lane&15, row = (lane>>4)*4 + reg
  int q = l >> 4;
  size_t rowbase = (size_t)(m0 + w * 16 + q * 4) * CC + n0 + ml;
  f32x4 accs[4] = {acc0, acc1, acc2, acc3};
  #pragma unroll
  for (int f = 0; f < 4; ++f)
    #pragma unroll
    for (int r = 0; r < 4; ++r)
      C[rowbase + (size_t)r * CC + f * 16] = f2b(accs[f][r]);
}

// ---- aggregation (gather-sum over CSR) -------------------------------------
// Y[e,b,:] = inv[e] * sum_{k in [off[e],off[e+1])} X[lst[k], b, :]  (+bias)
// Yf != null: write fp32 to [b][n][c] (final output). else bf16 node-major.
__global__ __launch_bounds__(256) void agg_k(const unsigned short* __restrict__ X,
                                             const int* __restrict__ off,
                                             const int* __restrict__ lst,
                                             const float* __restrict__ inv,
                                             const float* __restrict__ bias,
                                             unsigned short* __restrict__ Yb,
                                             float* __restrict__ Yf) {
  int pid = blockIdx.x * 4 + (threadIdx.x >> 6);  // (e,b) pair, e-major
  int e = pid >> 6, b = pid & 63;
  int t = threadIdx.x & 63;
  int beg = off[e], end = off[e + 1];
  float s0 = 0.f, s1 = 0.f, s2 = 0.f, s3 = 0.f;
  for (int k = beg; k < end; ++k) {
    int j = lst[k];
    ushort4 v = *(const ushort4*)(X + (((size_t)j << 6) + b) * CC + t * 4);
    s0 += b2f(v.x); s1 += b2f(v.y); s2 += b2f(v.z); s3 += b2f(v.w);
  }
  float sc = inv[e];
  s0 *= sc; s1 *= sc; s2 *= sc; s3 *= sc;
  if (bias) {
    s0 += bias[t * 4 + 0]; s1 += bias[t * 4 + 1];
    s2 += bias[t * 4 + 2]; s3 += bias[t * 4 + 3];
  }
  if (Yf) {
    float4 o4 = make_float4(s0, s1, s2, s3);
    *(float4*)(Yf + (((size_t)b << 12) + e) * CC + t * 4) = o4;
  } else {
    ushort4 o;
    o.x = f2b(s0); o.y = f2b(s1); o.z = f2b(s2); o.w = f2b(s3);
    *(ushort4*)(Yb + (((size_t)e << 6) + b) * CC + t * 4) = o;
  }
}

extern "C" void kernel_launch(void* const* d_in, const int* in_sizes, int n_in,
                              void* d_out, int out_size, void* d_ws, size_t ws_size,
                              hipStream_t stream) {
  const float* x  = (const float*)d_in[0];
  const int*   he = (const int*)d_in[1];
  const float* W1 = (const float*)d_in[2];
  const float* b1 = (const float*)d_in[3];
  const float* W2 = (const float*)d_in[4];
  const float* b2 = (const float*)d_in[5];
  const int* src = he;            // hyperedge_index[0]
  const int* dst = he + NNZK;     // hyperedge_index[1]
  float* out = (float*)d_out;

  char* ws = (char*)d_ws;
  size_t o = 0;
  auto alloc = [&](size_t bytes) {
    char* p = ws + o;
    o += (bytes + 255) & ~(size_t)255;
    return p;
  };
  unsigned short* xb  = (unsigned short*)alloc((size_t)MM * CC * 2); // x bf16 / h
  unsigned short* xw  = (unsigned short*)alloc((size_t)MM * CC * 2); // x@W / h@W
  unsigned short* edg = (unsigned short*)alloc((size_t)MM * CC * 2); // edge feats
  unsigned short* Wt1 = (unsigned short*)alloc((size_t)CC * CC * 2);
  unsigned short* Wt2 = (unsigned short*)alloc((size_t)CC * CC * 2);
  int* BdegI = (int*)alloc(NED * 4);
  int* DdegI = (int*)alloc(NND * 4);
  int* offB  = (int*)alloc((NED + 1) * 4);
  int* offD  = (int*)alloc((NND + 1) * 4);
  int* curB  = (int*)alloc(NED * 4);
  int* curD  = (int*)alloc(NND * 4);
  int* listB = (int*)alloc(NNZK * 4);
  int* listD = (int*)alloc(NNZK * 4);
  float* Binv = (float*)alloc(NED * 4);
  float* Dinv = (float*)alloc(NND * 4);

  hipMemsetAsync(BdegI, 0, NED * 4, stream);
  hipMemsetAsync(DdegI, 0, NND * 4, stream);

  hist_k<<<NNZK / 256, 256, 0, stream>>>(src, dst, DdegI, BdegI);
  scan_k<<<2, 256, 0, stream>>>(BdegI, offB, curB, Binv, DdegI, offD, curD, Dinv);
  fill_k<<<NNZK / 256, 256, 0, stream>>>(src, dst, curB, curD, listB, listD);

  cvt_x_k<<<(BB * NND) / 4, 256, 0, stream>>>(x, xb);
  cvt_w_k<<<CC, CC, 0, stream>>>(W1, Wt1);
  cvt_w_k<<<CC, CC, 0, stream>>>(W2, Wt2);

  dim3 gg(MM / 64, CC / 64);
  // layer 1
  gemm_tn<<<gg, 256, 0, stream>>>(xb, Wt1, xw);
  agg_k<<<NED * 16, 256, 0, stream>>>(xw, offB, listB, Binv, nullptr, edg, nullptr);
  agg_k<<<NND * 16, 256, 0, stream>>>(edg, offD, listD, Dinv, b1, xb, nullptr); // h -> xb
  // layer 2
  gemm_tn<<<gg, 256, 0, stream>>>(xb, Wt2, xw);
  agg_k<<<NED * 16, 256, 0, stream>>>(xw, offB, listB, Binv, nullptr, edg, nullptr);
  agg_k<<<NND * 16, 256, 0, stream>>>(edg, offD, listD, Dinv, b2, nullptr, out);
}

// Round 2
// 1259.711 us; speedup vs baseline: 1.2433x; 1.2433x over previous
//
#include <hip/hip_runtime.h>

#define NND 4096
#define NED 4096
#define NNZK 32768
#define BB 64
#define CC 256
#define MM (NND * BB)

typedef __attribute__((ext_vector_type(8))) __bf16 bf16x8;
typedef __attribute__((ext_vector_type(4))) float f32x4;

__device__ __forceinline__ float b2f(unsigned short h) {
  unsigned int v = ((unsigned int)h) << 16;
  return __builtin_bit_cast(float, v);
}
__device__ __forceinline__ unsigned short f2b(float f) {
  unsigned int v = __builtin_bit_cast(unsigned int, f);
  v = v + 0x7FFFu + ((v >> 16) & 1u);
  return (unsigned short)(v >> 16);
}
// accumulate packed pair of bf16 (low, high) into two fp32 accs
__device__ __forceinline__ void acc2(float& a0, float& a1, unsigned int v) {
  a0 += __builtin_bit_cast(float, v << 16);
  a1 += __builtin_bit_cast(float, v & 0xffff0000u);
}
__device__ __forceinline__ unsigned int pack2(float a0, float a1) {
  return (unsigned int)f2b(a0) | ((unsigned int)f2b(a1) << 16);
}

// ---- CSR build -------------------------------------------------------------
__global__ __launch_bounds__(256) void hist_k(const int* __restrict__ src,
                                              const int* __restrict__ dst,
                                              int* __restrict__ DdegI,
                                              int* __restrict__ BdegI) {
  int i = blockIdx.x * 256 + threadIdx.x;
  atomicAdd(&DdegI[src[i]], 1);
  atomicAdd(&BdegI[dst[i]], 1);
}

__global__ __launch_bounds__(256) void scan_k(const int* __restrict__ degB, int* __restrict__ offB,
                                              int* __restrict__ curB, float* __restrict__ invB,
                                              const int* __restrict__ degD, int* __restrict__ offD,
                                              int* __restrict__ curD, float* __restrict__ invD) {
  const int* deg; int* off; int* cur; float* inv;
  if (blockIdx.x == 0) { deg = degB; off = offB; cur = curB; inv = invB; }
  else                 { deg = degD; off = offD; cur = curD; inv = invD; }
  int t = threadIdx.x;
  int base = t * 16;
  int v[16]; int s = 0;
  #pragma unroll
  for (int i = 0; i < 16; ++i) { v[i] = deg[base + i]; s += v[i]; }
  __shared__ int sm[256];
  sm[t] = s;
  __syncthreads();
  for (int d = 1; d < 256; d <<= 1) {
    int x = (t >= d) ? sm[t - d] : 0;
    __syncthreads();
    sm[t] += x;
    __syncthreads();
  }
  int excl = sm[t] - s;
  #pragma unroll
  for (int i = 0; i < 16; ++i) {
    off[base + i] = excl;
    cur[base + i] = excl;
    int dv = v[i];
    inv[base + i] = (dv > 0) ? (1.0f / (float)dv) : 0.0f;
    excl += dv;
  }
  if (t == 255) off[4096] = excl;
}

__global__ __launch_bounds__(256) void fill_k(const int* __restrict__ src,
                                              const int* __restrict__ dst,
                                              int* __restrict__ curB, int* __restrict__ curD,
                                              int* __restrict__ listB, int* __restrict__ listD) {
  int i = blockIdx.x * 256 + threadIdx.x;
  int s = src[i], d = dst[i];
  int p = atomicAdd(&curB[d], 1);
  listB[p] = s;
  int q = atomicAdd(&curD[s], 1);
  listD[q] = d;
}

// ---- converts --------------------------------------------------------------
__global__ __launch_bounds__(256) void cvt_x_k(const float* __restrict__ x,
                                               unsigned short* __restrict__ xb) {
  int blk = blockIdx.x * 4 + (threadIdx.x >> 6);
  int b = blk >> 12, n = blk & 4095;
  int t = threadIdx.x & 63;
  float4 v = *(const float4*)(x + (size_t)blk * CC + t * 4);
  ushort4 o;
  o.x = f2b(v.x); o.y = f2b(v.y); o.z = f2b(v.z); o.w = f2b(v.w);
  *(ushort4*)(xb + (((size_t)n << 6) + b) * CC + t * 4) = o;
}

__global__ __launch_bounds__(256) void cvt_w_k(const float* __restrict__ W,
                                               unsigned short* __restrict__ Wt) {
  int k = blockIdx.x, n = threadIdx.x;
  Wt[n * CC + k] = f2b(W[k * CC + n]);
}

// ---- 128x128 bf16 MFMA GEMM: C[m][n] = sum_k A[m][k] * Bt[n][k] ------------
__global__ __launch_bounds__(256) void gemm128(const unsigned short* __restrict__ A,
                                               const unsigned short* __restrict__ Bt,
                                               unsigned short* __restrict__ C) {
  __shared__ __align__(16) unsigned short Al[128][40];  // +8 pad -> 2-way banks (free)
  __shared__ __align__(16) unsigned short Bl[128][40];
  int t = threadIdx.x;
  int w = t >> 6, l = t & 63;
  int wm = w >> 1, wn = w & 1;
  int m0 = blockIdx.x * 128, n0 = blockIdx.y * 128;
  int ml = l & 15, ko = (l >> 4) * 8;
  f32x4 acc[4][4] = {};
  int sr = t >> 2, sc = (t & 3) * 8;            // 64 rows x 64B per pass, x2
  const unsigned short* Ap = A  + (size_t)(m0 + sr) * CC + sc;
  const unsigned short* Bp = Bt + (size_t)(n0 + sr) * CC + sc;
  for (int kt = 0; kt < 8; ++kt) {
    uint4 a0v = *(const uint4*)(Ap + kt * 32);
    uint4 a1v = *(const uint4*)(Ap + (size_t)64 * CC + kt * 32);
    uint4 b0v = *(const uint4*)(Bp + kt * 32);
    uint4 b1v = *(const uint4*)(Bp + (size_t)64 * CC + kt * 32);
    __syncthreads();
    *(uint4*)&Al[sr][sc]      = a0v;
    *(uint4*)&Al[64 + sr][sc] = a1v;
    *(uint4*)&Bl[sr][sc]      = b0v;
    *(uint4*)&Bl[64 + sr][sc] = b1v;
    __syncthreads();
    bf16x8 af[4], bf[4];
    #pragma unroll
    for (int i = 0; i < 4; ++i) {
      af[i] = __builtin_bit_cast(bf16x8, *(const uint4*)&Al[wm * 64 + i * 16 + ml][ko]);
      bf[i] = __builtin_bit_cast(bf16x8, *(const uint4*)&Bl[wn * 64 + i * 16 + ml][ko]);
    }
    #pragma unroll
    for (int i = 0; i < 4; ++i)
      #pragma unroll
      for (int j = 0; j < 4; ++j)
        acc[i][j] = __builtin_amdgcn_mfma_f32_16x16x32_bf16(af[i], bf[j], acc[i][j], 0, 0, 0);
  }
  int q = l >> 4;
  #pragma unroll
  for (int i = 0; i < 4; ++i) {
    size_t rowb = (size_t)(m0 + wm * 64 + i * 16 + q * 4) * CC + n0 + wn * 64 + ml;
    #pragma unroll
    for (int j = 0; j < 4; ++j)
      #pragma unroll
      for (int r = 0; r < 4; ++r)
        C[rowb + (size_t)r * CC + j * 16] = f2b(acc[i][j][r]);
  }
}

// ---- aggregation: block per (segment e, batch-half) ------------------------
// For each j in CSR list of e: stream 16KB contiguous (32 batches x 256 ch bf16),
// accumulate 32 fp32/thread in registers. Then scale by inv[e] (+bias) and write.
__global__ __launch_bounds__(256) void agg2_k(const unsigned short* __restrict__ X,
                                              const int* __restrict__ off,
                                              const int* __restrict__ lst,
                                              const float* __restrict__ inv,
                                              const float* __restrict__ bias,
                                              unsigned short* __restrict__ Yb,
                                              float* __restrict__ Yf) {
  int e = blockIdx.x >> 1, half = blockIdx.x & 1;
  int t = threadIdx.x;
  int beg = off[e], end = off[e + 1];
  float acc[32];
  #pragma unroll
  for (int i = 0; i < 32; ++i) acc[i] = 0.f;
  const char* Xb = (const char*)X + (size_t)half * 16384 + (size_t)t * 16;
  for (int k = beg; k < end; ++k) {
    int j = lst[k];
    const char* rp = Xb + (size_t)j * 32768;
    #pragma unroll
    for (int i = 0; i < 4; ++i) {
      uint4 v = *(const uint4*)(rp + i * 4096);
      acc2(acc[i * 8 + 0], acc[i * 8 + 1], v.x);
      acc2(acc[i * 8 + 2], acc[i * 8 + 3], v.y);
      acc2(acc[i * 8 + 4], acc[i * 8 + 5], v.z);
      acc2(acc[i * 8 + 6], acc[i * 8 + 7], v.w);
    }
  }
  float sc = inv[e];
  float bv[8];
  if (bias) {
    float4 bb0 = *(const float4*)(bias + (t & 31) * 8);
    float4 bb1 = *(const float4*)(bias + (t & 31) * 8 + 4);
    bv[0] = bb0.x; bv[1] = bb0.y; bv[2] = bb0.z; bv[3] = bb0.w;
    bv[4] = bb1.x; bv[5] = bb1.y; bv[6] = bb1.z; bv[7] = bb1.w;
  } else {
    #pragma unroll
    for (int j2 = 0; j2 < 8; ++j2) bv[j2] = 0.f;
  }
  #pragma unroll
  for (int i = 0; i < 32; ++i) acc[i] = acc[i] * sc + bv[i & 7];
  if (Yf) {
    int c0 = (t & 31) * 8;
    #pragma unroll
    for (int i = 0; i < 4; ++i) {
      int b = half * 32 + (t >> 5) + i * 8;
      float* op = Yf + ((size_t)b * 4096 + e) * 256 + c0;
      float4 o0 = make_float4(acc[i * 8 + 0], acc[i * 8 + 1], acc[i * 8 + 2], acc[i * 8 + 3]);
      float4 o1 = make_float4(acc[i * 8 + 4], acc[i * 8 + 5], acc[i * 8 + 6], acc[i * 8 + 7]);
      *(float4*)op = o0;
      *(float4*)(op + 4) = o1;
    }
  } else {
    char* wp = (char*)Yb + (size_t)e * 32768 + (size_t)half * 16384 + (size_t)t * 16;
    #pragma unroll
    for (int i = 0; i < 4; ++i) {
      uint4 o;
      o.x = pack2(acc[i * 8 + 0], acc[i * 8 + 1]);
      o.y = pack2(acc[i * 8 + 2], acc[i * 8 + 3]);
      o.z = pack2(acc[i * 8 + 4], acc[i * 8 + 5]);
      o.w = pack2(acc[i * 8 + 6], acc[i * 8 + 7]);
      *(uint4*)(wp + i * 4096) = o;
    }
  }
}

extern "C" void kernel_launch(void* const* d_in, const int* in_sizes, int n_in,
                              void* d_out, int out_size, void* d_ws, size_t ws_size,
                              hipStream_t stream) {
  const float* x  = (const float*)d_in[0];
  const int*   he = (const int*)d_in[1];
  const float* W1 = (const float*)d_in[2];
  const float* b1 = (const float*)d_in[3];
  const float* W2 = (const float*)d_in[4];
  const float* b2 = (const float*)d_in[5];
  const int* src = he;
  const int* dst = he + NNZK;
  float* out = (float*)d_out;

  char* ws = (char*)d_ws;
  size_t o = 0;
  auto alloc = [&](size_t bytes) {
    char* p = ws + o;
    o += (bytes + 255) & ~(size_t)255;
    return p;
  };
  unsigned short* xb  = (unsigned short*)alloc((size_t)MM * CC * 2);
  unsigned short* xw  = (unsigned short*)alloc((size_t)MM * CC * 2);
  unsigned short* edg = (unsigned short*)alloc((size_t)MM * CC * 2);
  unsigned short* Wt1 = (unsigned short*)alloc((size_t)CC * CC * 2);
  unsigned short* Wt2 = (unsigned short*)alloc((size_t)CC * CC * 2);
  int* BdegI = (int*)alloc(NED * 4);
  int* DdegI = (int*)alloc(NND * 4);
  int* offB  = (int*)alloc((NED + 1) * 4);
  int* offD  = (int*)alloc((NND + 1) * 4);
  int* curB  = (int*)alloc(NED * 4);
  int* curD  = (int*)alloc(NND * 4);
  int* listB = (int*)alloc(NNZK * 4);
  int* listD = (int*)alloc(NNZK * 4);
  float* Binv = (float*)alloc(NED * 4);
  float* Dinv = (float*)alloc(NND * 4);

  hipMemsetAsync(BdegI, 0, NED * 4, stream);
  hipMemsetAsync(DdegI, 0, NND * 4, stream);

  hist_k<<<NNZK / 256, 256, 0, stream>>>(src, dst, DdegI, BdegI);
  scan_k<<<2, 256, 0, stream>>>(BdegI, offB, curB, Binv, DdegI, offD, curD, Dinv);
  fill_k<<<NNZK / 256, 256, 0, stream>>>(src, dst, curB, curD, listB, listD);

  cvt_x_k<<<(BB * NND) / 4, 256, 0, stream>>>(x, xb);
  cvt_w_k<<<CC, CC, 0, stream>>>(W1, Wt1);
  cvt_w_k<<<CC, CC, 0, stream>>>(W2, Wt2);

  dim3 gg(MM / 128, CC / 128);
  // layer 1
  gemm128<<<gg, 256, 0, stream>>>(xb, Wt1, xw);
  agg2_k<<<NED * 2, 256, 0, stream>>>(xw, offB, listB, Binv, nullptr, edg, nullptr);
  agg2_k<<<NND * 2, 256, 0, stream>>>(edg, offD, listD, Dinv, b1, xb, nullptr);
  // layer 2
  gemm128<<<gg, 256, 0, stream>>>(xb, Wt2, xw);
  agg2_k<<<NED * 2, 256, 0, stream>>>(xw, offB, listB, Binv, nullptr, edg, nullptr);
  agg2_k<<<NND * 2, 256, 0, stream>>>(edg, offD, listD, Dinv, b2, nullptr, out);
}